// Round 8
// baseline (231.016 us; speedup 1.0000x reference)
//
#include <hip/hip_runtime.h>

// ---------------------------------------------------------------------------
// CustomMultiHeadAttentionStoich: fused MHA with RoPE + frac-difference bias.
// B=2 T=2048 D_MODEL=1024 H=16 hd=64. All matmuls via mfma_f32_16x16x32_bf16.
//
// Verified gfx950 fragment layouts (learn_hip m89/m91, rounds 1-6 pass):
//   A-frag : lane holds A[m=lane&15][k=(lane>>4)*8 + j], j=0..7  (8 bf16, 16B)
//   B-frag : lane holds B[k=(lane>>4)*8 + j][n=lane&15]
//   C/D    : lane holds D[row=(lane>>4)*4 + r][col=lane&15], r=0..3 (4 f32)
//
// Round-15: R7 (= R4 + setprio only) FAILED nondeterministically => latent
// timing hazard present even in the R4-passing binary. Identified mechanism:
// back-to-back INLINE-ASM v_cvt_pk_bf16_f32 (VALU write) -> v_permlane*_swap
// (cross-lane read) -> MFMA chain has required HW wait-states that LLVM's
// hazard recognizer does NOT insert across inline-asm boundaries (it treats
// asm as opaque). Whether the window is hit depends on pipeline timing --
// which is exactly what setprio (R7) and occupancy changes (R5/R6) perturb;
// R4 was a lucky draw. Fix: explicit s_nop wait-state guards inside the
// cvt_pk/permlane sequence (cost ~6 cyc/tile/wave). NO setprio. Everything
// else byte-identical to the R4-passing kernel (230.6us).
// ---------------------------------------------------------------------------

typedef unsigned short u16;
typedef __bf16 bf8v __attribute__((ext_vector_type(8)));
typedef __bf16 bf4v __attribute__((ext_vector_type(4)));
typedef float f32x4 __attribute__((ext_vector_type(4)));
typedef unsigned int u32x4v __attribute__((ext_vector_type(4)));

#define D_MODEL 1024
#define T_SEQ   2048
#define NHEAD   16
#define HDIM    64
#define BATCH   2
#define M_TOT   (BATCH * T_SEQ) /* 4096 */
#define LOG2E   1.4426950408889634f

__device__ __forceinline__ void gl2lds16(const u16* g, u16* l) {
  __builtin_amdgcn_global_load_lds(
      (__attribute__((address_space(1))) void*)g,
      (__attribute__((address_space(3))) void*)l, 16, 0, 0);
}

// ---------------------------------------------------------------------------
// k_prep: zone-partitioned prep work in ONE launch.
//   blocks [0,6144)    : f32->bf16 convert of q/k/v into Xb
//   blocks [6144,7168) : W^T bf16 transpose of Wq/Wk/Wv/Wo into WtB
//   blocks [7168,7424) : RoPE cos/sin table
__global__ __launch_bounds__(256) void k_prep(
    const float* __restrict__ q, const float* __restrict__ k,
    const float* __restrict__ v, const float* __restrict__ Wq,
    const float* __restrict__ Wk, const float* __restrict__ Wv,
    const float* __restrict__ Wo, u16* __restrict__ Xb, u16* __restrict__ WtB,
    float* __restrict__ ct, float* __restrict__ st) {
  __shared__ float tile[64 * 65];
  int bx = blockIdx.x, tid = threadIdx.x;
  if (bx < 6144) { // ---- convert zone
    int z = bx >> 11, xb = bx & 2047;
    const float* src = (z == 0) ? q : (z == 1) ? k : v;
    u16* dst = Xb + (size_t)z * (M_TOT * D_MODEL);
    int idx = (xb * 256 + tid) * 8;
    float4 a = *(const float4*)(src + idx);
    float4 b = *(const float4*)(src + idx + 4);
    bf8v o;
    o[0] = (__bf16)a.x; o[1] = (__bf16)a.y; o[2] = (__bf16)a.z; o[3] = (__bf16)a.w;
    o[4] = (__bf16)b.x; o[5] = (__bf16)b.y; o[6] = (__bf16)b.z; o[7] = (__bf16)b.w;
    *(bf8v*)(dst + idx) = o;
  } else if (bx < 7168) { // ---- W transpose zone (64x64 tiles, stride 65)
    int idx2 = bx - 6144;
    int z = idx2 >> 8, rem = idx2 & 255;
    int k0 = (rem >> 4) * 64, n0 = (rem & 15) * 64;
    const float* W = (z == 0) ? Wq : (z == 1) ? Wk : (z == 2) ? Wv : Wo;
    u16* Wt = WtB + (size_t)z * (D_MODEL * D_MODEL);
#pragma unroll
    for (int i = 0; i < 16; i++) {
      int idx = tid + i * 256;
      int r = idx >> 6, c = idx & 63;
      tile[c * 65 + r] = W[(size_t)(k0 + r) * D_MODEL + n0 + c];
    }
    __syncthreads();
#pragma unroll
    for (int i = 0; i < 16; i++) {
      int idx = tid + i * 256;
      int r = idx >> 6, c = idx & 63;
      ((__bf16*)Wt)[(size_t)(n0 + r) * D_MODEL + k0 + c] = (__bf16)tile[r * 65 + c];
    }
  } else { // ---- RoPE table zone: angle(t,d) = t / 10000^(d/32)
    int idx = (bx - 7168) * 256 + tid; // = t*32 + d
    int t = idx >> 5, d = idx & 31;
    float ang = (float)t * powf(10000.0f, -(float)d * (1.0f / 32.0f));
    ct[idx] = cosf(ang);
    st[idx] = sinf(ang);
  }
}

// ---------------------------------------------------------------------------
// QKV GEMM core v2: C = A[M][K] @ Bt[N][K]^T, K=1024, BK=64, BM=BN=128.
// DOUBLE-buffered global_load_lds staging with counted vmcnt:
//   per iter: B1(s_barrier: all reads of buf[t-1] done) -> stage(t+1) ->
//   vmcnt(8) (own stage(t) landed; stage(t+1) flying) -> B2(s_barrier:
//   ALL waves' stage(t) landed) -> ds_read+MFMA on buf[t].
// No vmcnt(0) drain in the main loop.
__device__ __forceinline__ void gemm_core_128(const u16* __restrict__ A,
                                              const u16* __restrict__ Bt,
                                              u16* sA, u16* sB,
                                              f32x4 (&acc)[4][4],
                                              int m0, int n0) {
  const int K = D_MODEL;
  const int NT = K / 64; // 16
  int tid = threadIdx.x;
  int lane = tid & 63, wave = tid >> 6;
  int l15 = lane & 15, quad = lane >> 4;
  int wm = (wave >> 1) * 64, wn = (wave & 1) * 64;
  int r0 = tid >> 2, pcol0 = (tid & 3) * 8;
  int r1 = 64 + r0;
  const u16* A0 = A + (size_t)(m0 + r0) * K + pcol0;
  const u16* A1 = A + (size_t)(m0 + r1) * K + pcol0;
  const u16* B0 = Bt + (size_t)(n0 + r0) * K + pcol0;
  const u16* B1 = Bt + (size_t)(n0 + r1) * K + pcol0;
  u16* dA0 = sA + wave * 512;        // plane0, rows 0..63 (wave-uniform base)
  u16* dA1 = sA + 2048 + wave * 512; // plane0, rows 64..127
  u16* dB0 = sB + wave * 512;
  u16* dB1 = sB + 2048 + wave * 512;
  auto stg = [&](int bo, int k0) {
    gl2lds16(A0 + k0, dA0 + bo);
    gl2lds16(A1 + k0, dA1 + bo);
    gl2lds16(A0 + k0 + 32, dA0 + 4096 + bo); // plane1
    gl2lds16(A1 + k0 + 32, dA1 + 4096 + bo);
    gl2lds16(B0 + k0, dB0 + bo);
    gl2lds16(B0 + k0 + 32, dB0 + 4096 + bo);
    gl2lds16(B1 + k0, dB1 + bo);
    gl2lds16(B1 + k0 + 32, dB1 + 4096 + bo);
  };
  stg(0, 0);
  for (int t = 0; t < NT; t++) {
    int bo = (t & 1) * 8192;
    __builtin_amdgcn_s_barrier(); // B1: all waves done reading buf[t-1]
    if (t + 1 < NT) {
      stg(bo ^ 8192, (t + 1) * 64);
      asm volatile("s_waitcnt vmcnt(8)" ::: "memory"); // stage(t) landed
    } else {
      asm volatile("s_waitcnt vmcnt(0)" ::: "memory"); // last: drain
    }
    __builtin_amdgcn_s_barrier(); // B2: all waves' stage(t) landed
#pragma unroll
    for (int kh = 0; kh < 2; kh++) {
      bf8v af[4], bf[4];
#pragma unroll
      for (int i = 0; i < 4; i++)
        af[i] = *(const bf8v*)(sA + bo + kh * 4096 + (wm + i * 16 + l15) * 32 + quad * 8);
#pragma unroll
      for (int i = 0; i < 4; i++)
        bf[i] = *(const bf8v*)(sB + bo + kh * 4096 + (wn + i * 16 + l15) * 32 + quad * 8);
#pragma unroll
      for (int mi = 0; mi < 4; mi++)
#pragma unroll
        for (int ni = 0; ni < 4; ni++)
          acc[mi][ni] = __builtin_amdgcn_mfma_f32_16x16x32_bf16(
              af[mi], bf[ni], acc[mi][ni], 0, 0, 0);
    }
  }
}

// QKV projection, grid (8, 32, 3). XCD-swizzled: XCD = bx (lin%8); each XCD
// owns 4 consecutive m-panels x all 8 n-blocks -> A 1MB + B 2MB L2-resident.
// z<2 -> RoPE fused; z==0 prescales Q by 0.125*log2e. z==2 writes projected
// V DIRECTLY TRANSPOSED into Vb[b][h][d][t].
__global__ __launch_bounds__(256) void k_gemm_qkv(
    const u16* __restrict__ Xb, const u16* __restrict__ WtB,
    const float* __restrict__ bq, const float* __restrict__ bk,
    const float* __restrict__ bv, const float* __restrict__ ctab,
    const float* __restrict__ stab, u16* __restrict__ OutB,
    u16* __restrict__ Vb) {
  __shared__ __align__(16) u16 sA[2 * 128 * 64];
  __shared__ __align__(16) u16 sB[2 * 128 * 64];
  int z = blockIdx.z;
  const u16* A = Xb + (size_t)z * (M_TOT * D_MODEL);
  const u16* Bt = WtB + (size_t)z * (D_MODEL * D_MODEL);
  const float* bias = (z == 0) ? bq : (z == 1) ? bk : bv;
  u16* Out = OutB + (size_t)z * (M_TOT * D_MODEL);
  // XCD swizzle: xcd = blockIdx.x (grid x=8; lin%8 = bx since 8|8*by, 8|256*bz)
  int mblk = (blockIdx.x << 2) | (blockIdx.y >> 3);
  int nblk = blockIdx.y & 7;
  int m0 = mblk * 128, n0 = nblk * 128;
  f32x4 acc[4][4] = {};
  gemm_core_128(A, Bt, sA, sB, acc, m0, n0);

  int tid = threadIdx.x, lane = tid & 63, wave = tid >> 6;
  int l15 = lane & 15, quad = lane >> 4;
  int wm = (wave >> 1) * 64, wn = (wave & 1) * 64;
  float bvv[4];
#pragma unroll
  for (int ni = 0; ni < 4; ni++) bvv[ni] = bias[n0 + wn + ni * 16 + l15];

  if (z < 2) { // Q/K: RoPE fused; Q also prescaled 0.125*log2e
    float qs = (z == 0) ? 0.125f * LOG2E : 1.0f;
#pragma unroll
    for (int mi = 0; mi < 4; mi++) {
#pragma unroll
      for (int r = 0; r < 4; r++) {
        int m = m0 + wm + mi * 16 + quad * 4 + r; // global row = b*T + t
        size_t ro = (size_t)m * D_MODEL + n0 + wn;
        int tl = m & (T_SEQ - 1);
#pragma unroll
        for (int ni = 0; ni < 2; ni++) {
          int d = ni * 16 + l15; // < 32; pair (d, d+32) in regs ni, ni+2
          float c = ctab[tl * 32 + d], s = stab[tl * 32 + d];
          float xl = acc[mi][ni][r] + bvv[ni];
          float xr = acc[mi][ni + 2][r] + bvv[ni + 2];
          ((__bf16*)Out)[ro + d] = (__bf16)((xl * c - xr * s) * qs);
          ((__bf16*)Out)[ro + d + 32] = (__bf16)((xl * s + xr * c) * qs);
        }
      }
    }
  } else { // V: write transposed Vb[b][h][d][t] (wave's 64 cols = one head)
    int hh = (n0 + wn) >> 6;
    int mbase = m0 + wm;
    int bb = mbase >> 11; // tile never crosses batch (2048 % 128 == 0)
    int tbase = mbase & (T_SEQ - 1);
    u16* Vw = Vb + (size_t)(bb * NHEAD + hh) * HDIM * T_SEQ;
#pragma unroll
    for (int mi = 0; mi < 4; mi++)
#pragma unroll
      for (int r = 0; r < 4; r++) {
        int t = tbase + mi * 16 + quad * 4 + r;
#pragma unroll
        for (int ni = 0; ni < 4; ni++) {
          int d = ni * 16 + l15;
          ((__bf16*)Vw)[(size_t)d * T_SEQ + t] = (__bf16)(acc[mi][ni][r] + bvv[ni]);
        }
      }
  }
}

// Output projection: ctx bf16 @ Wo^T + bo -> f32 d_out. 64x64 tiles, grid
// (16, 64) = 1024 blocks, XCD-swizzled (8 m-panels x 16 n per XCD: A 1MB +
// B 2MB L2-resident). Double-buffered staging with counted vmcnt(4).
__global__ __launch_bounds__(256) void k_gemm_out(
    const u16* __restrict__ ctx, const u16* __restrict__ Wot,
    const float* __restrict__ bo, float* __restrict__ Cout) {
  __shared__ __align__(16) u16 sA[2 * 64 * 64];
  __shared__ __align__(16) u16 sB[2 * 64 * 64];
  const int K = D_MODEL;
  const int NT = K / 64; // 16
  // XCD swizzle: lin = bx + 16*by -> xcd = bx&7. Per-xcd slot: (bx>>3)*64+by.
  int xcd = blockIdx.x & 7;
  int idx = ((blockIdx.x >> 3) << 6) | blockIdx.y; // 0..127
  int m0 = (xcd * 8 + (idx >> 4)) * 64;
  int n0 = (idx & 15) * 64;
  int tid = threadIdx.x, lane = tid & 63, wave = tid >> 6;
  int l15 = lane & 15, quad = lane >> 4;
  int wm = (wave >> 1) * 32, wn = (wave & 1) * 32;
  int r0 = tid >> 2, pcol0 = (tid & 3) * 8;
  const u16* A0 = ctx + (size_t)(m0 + r0) * K + pcol0;
  const u16* B0 = Wot + (size_t)(n0 + r0) * K + pcol0;
  u16* dA = sA + wave * 512; // one call = one full 64x32 plane (256 thr)
  u16* dB = sB + wave * 512;
  auto stg = [&](int bo, int k0) {
    gl2lds16(A0 + k0, dA + bo);
    gl2lds16(A0 + k0 + 32, dA + 2048 + bo); // plane1
    gl2lds16(B0 + k0, dB + bo);
    gl2lds16(B0 + k0 + 32, dB + 2048 + bo);
  };
  f32x4 acc[2][2] = {};
  stg(0, 0);
  for (int t = 0; t < NT; t++) {
    int bo = (t & 1) * 4096;
    __builtin_amdgcn_s_barrier(); // B1: all waves done reading buf[t-1]
    if (t + 1 < NT) {
      stg(bo ^ 4096, (t + 1) * 64);
      asm volatile("s_waitcnt vmcnt(4)" ::: "memory"); // stage(t) landed
    } else {
      asm volatile("s_waitcnt vmcnt(0)" ::: "memory");
    }
    __builtin_amdgcn_s_barrier(); // B2: all waves' stage(t) landed
#pragma unroll
    for (int kh = 0; kh < 2; kh++) {
      bf8v af[2], bf[2];
#pragma unroll
      for (int i = 0; i < 2; i++)
        af[i] = *(const bf8v*)(sA + bo + kh * 2048 + (wm + i * 16 + l15) * 32 + quad * 8);
#pragma unroll
      for (int i = 0; i < 2; i++)
        bf[i] = *(const bf8v*)(sB + bo + kh * 2048 + (wn + i * 16 + l15) * 32 + quad * 8);
#pragma unroll
      for (int mi = 0; mi < 2; mi++)
#pragma unroll
        for (int ni = 0; ni < 2; ni++)
          acc[mi][ni] = __builtin_amdgcn_mfma_f32_16x16x32_bf16(
              af[mi], bf[ni], acc[mi][ni], 0, 0, 0);
    }
  }
  float bvv[2];
#pragma unroll
  for (int ni = 0; ni < 2; ni++) bvv[ni] = bo[n0 + wn + ni * 16 + l15];
#pragma unroll
  for (int mi = 0; mi < 2; mi++)
#pragma unroll
    for (int r = 0; r < 4; r++) {
      size_t ro = (size_t)(m0 + wm + mi * 16 + quad * 4 + r) * D_MODEL + n0 + wn;
#pragma unroll
      for (int ni = 0; ni < 2; ni++)
        Cout[ro + ni * 16 + l15] = acc[mi][ni][r] + bvv[ni];
    }
}

// ---------------------------------------------------------------------------
// Flash attention v10h (R4-exact + inline-asm hazard guards): grid
// (T/128, B*H) XCD-swizzled, 512 thr = 8 waves. Wave w: q sub-tile qw = w&3
// (32 rows), key half kh = w>>2. exp2-native softmax without max-subtraction
// => key halves accumulate independent unnormalized (O, l), merged once at
// the end via LDS. K/V double-buffered global_load_lds DMA, ONE
// __syncthreads per tile. P transpose IN-REGISTER (cvt_pk + permlane swaps)
// with EXPLICIT s_nop wait-states (LLVM does not insert hazard nops across
// inline-asm boundaries; VALU-write -> cross-lane-read needs wait states).
__global__ __launch_bounds__(512, 4) void k_attn(
    const u16* __restrict__ Qr, const u16* __restrict__ Kr,
    const u16* __restrict__ Vb, const float* __restrict__ frac,
    const float* __restrict__ alpha_pos, const float* __restrict__ alpha_neg,
    u16* __restrict__ ctx) {
  // smem carve (u16 elems):
  //   [0,8192)       kT[2][4096]  swizzled [key][d]
  //   [8192,16384)   vT[2][4096]  swizzled [d][key]
  //   [16384,20480)  fLds: f32[2048] frac row for this batch
  // merge phase reuses [0,16896) as f32 O-scratch, [16896,17152) l-scratch.
  __shared__ __align__(16) u16 smem[20480];
  // ---- XCD swizzle: lin%8 = XCD (round-robin). Give each XCD 4 whole heads
  // so all 16 q-blocks of a head share one L2 (K/V single-fetch per XCD).
  int lin = blockIdx.x + (blockIdx.y << 4);
  int xcd = lin & 7, slot = lin >> 3;
  int bh = (xcd << 2) | (slot >> 4);
  int q0 = (slot & 15) << 7;
  int b = bh >> 4, h = bh & 15;
  int tid = threadIdx.x, wave = tid >> 6, lane = tid & 63;
  int l15 = lane & 15, quad = lane >> 4;
  int qw = wave & 3;  // q sub-tile (32 rows)
  int kh = wave >> 2; // key half within each 64-key tile

  const u16* Kh = Kr + (size_t)b * T_SEQ * D_MODEL + h * HDIM;
  const u16* Vh = Vb + (size_t)bh * HDIM * T_SEQ;
  const float* fb = frac + b * T_SEQ;

  u16* kT0 = smem;
  u16* vT0 = smem + 8192;
  float* fl = (float*)(smem + 16384);

  // Q B-frags (B[k=d][n=q] = Q[q][d]): lane holds Q[q=l15][d=quad*8+j]
  bf8v qf[2][2];
  float fq[2];
#pragma unroll
  for (int g = 0; g < 2; g++) {
    int qrow = q0 + qw * 32 + g * 16 + l15;
    const u16* qbase =
        Qr + (size_t)(b * T_SEQ + qrow) * D_MODEL + h * HDIM + quad * 8;
    qf[g][0] = *(const bf8v*)qbase;
    qf[g][1] = *(const bf8v*)(qbase + 32);
    fq[g] = fb[qrow]; // S^T col = q = l15
  }
  // frac -> LDS (512 thr x 4 floats = 2048)
  {
    f32x4 fv = *(const f32x4*)(fb + (tid << 2));
    *(f32x4*)(fl + (tid << 2)) = fv;
  }

  // bias = ap*max(dd,0)+an*min(dd,0) = c1*dd + c2*|dd| (log2 domain)
  float ap = alpha_pos[h] * LOG2E, an = alpha_neg[h] * LOG2E;
  float c1 = 0.5f * (ap + an), c2 = 0.5f * (ap - an);
  bf8v onesv;
#pragma unroll
  for (int j = 0; j < 8; j++) onesv[j] = (__bf16)1.0f;
  f32x4 zero4 = {};
  f32x4 o[2][4] = {};
  f32x4 o_l[2] = {};

  // Hoisted frag offsets (elems). Swizzle: row r, chunk gc -> pc = gc^(r&7).
  int x0 = (quad ^ (l15 & 7)) * 8;
  int kidx[2], vidx[4];
#pragma unroll
  for (int nt = 0; nt < 2; nt++) // K rows kh*32 + nt*16 + l15
    kidx[nt] = (((kh * 2 + nt) * 16 + l15) << 6) + x0;
#pragma unroll
  for (int dt = 0; dt < 4; dt++) // V keys chunk quad + kh*4
    vidx[dt] = (((dt * 16 + l15) << 6) + x0) ^ (kh * 32);

  // DMA staging map: 512 threads x 1 chunk per array per tile.
  // chunk p = tid; row = p>>3, pc = p&7; fetch global chunk gc = pc^(row&7).
  int kr0 = tid >> 3, gc0 = (tid & 7) ^ (kr0 & 7);
  const u16* kg0 = Kh + (size_t)kr0 * D_MODEL + gc0 * 8;
  const u16* vg0 = Vh + (size_t)kr0 * T_SEQ + gc0 * 8; // row = d here
  int woff = wave * 512; // wave-uniform LDS dest (elems); lane -> +lane*8

  auto stage = [&](int bufoff, int kbase) {
    gl2lds16(kg0 + (size_t)kbase * D_MODEL, kT0 + bufoff + woff);
    gl2lds16(vg0 + kbase, vT0 + bufoff + woff);
  };

  stage(0, 0);
  __syncthreads(); // DMA + frac-LDS visible

#pragma unroll 2
  for (int kt = 0; kt < T_SEQ / 64; kt++) {
    int kbase = kt * 64;
    int bo = (kt & 1) * 4096;
    if (kt + 1 < T_SEQ / 64) stage(bo ^ 4096, kbase + 64);
    const u16* kb = kT0 + bo;
    const u16* vb = vT0 + bo;

    // K A-frags for this wave's key half: rows kh*32 + nt*16 + l15
    bf8v kf0[2], kf1[2];
#pragma unroll
    for (int nt = 0; nt < 2; nt++) {
      kf0[nt] = *(const bf8v*)(kb + kidx[nt]);
      kf1[nt] = *(const bf8v*)(kb + (kidx[nt] ^ 32));
    }
    // V B-frags: rows d = dt*16+l15; key chunks kh*4 + quad
    bf8v vf[4];
#pragma unroll
    for (int dt = 0; dt < 4; dt++) vf[dt] = *(const bf8v*)(vb + vidx[dt]);
    // frac[key] for this lane's 4 keys per nt (LDS, 16-lane broadcast)
    f32x4 fk4[2];
#pragma unroll
    for (int nt = 0; nt < 2; nt++)
      fk4[nt] = *(const f32x4*)(fl + kbase + kh * 32 + nt * 16 + quad * 4);

#pragma unroll
    for (int g = 0; g < 2; g++) {
      float fqg = fq[g];
      // wrd = [A0, A1, B0, B1]: A_m from nt0 keys {4q+2m,+1}, B_m from nt1.
      unsigned int wrd[4];
#pragma unroll
      for (int nt = 0; nt < 2; nt++) {
        // S^T tile: D[row=key_loc=nt*16+quad*4+r][col=q=l15], log2 domain
        f32x4 s = zero4;
        s = __builtin_amdgcn_mfma_f32_16x16x32_bf16(kf0[nt], qf[g][0], s, 0, 0, 0);
        s = __builtin_amdgcn_mfma_f32_16x16x32_bf16(kf1[nt], qf[g][1], s, 0, 0, 0);
        float p[4];
#pragma unroll
        for (int r = 0; r < 4; r++) {
          float dd = fk4[nt][r] - fqg;
          p[r] = __builtin_amdgcn_exp2f(
              fmaf(c2, __builtin_fabsf(dd), fmaf(c1, dd, s[r])));
        }
        unsigned int w0, w1;
        asm("v_cvt_pk_bf16_f32 %0, %1, %2" : "=v"(w0) : "v"(p[0]), "v"(p[1]));
        asm("v_cvt_pk_bf16_f32 %0, %1, %2" : "=v"(w1) : "v"(p[2]), "v"(p[3]));
        wrd[nt * 2 + 0] = w0;
        wrd[nt * 2 + 1] = w1;
      }
      // In-register P transpose. permlane32_swap: X'={Xq0,Xq1,Yq0,Yq1},
      // Y'={Xq2,Xq3,Yq2,Yq3}. permlane16_swap: X''={X'r0,Y'r0,X'r2,Y'r2},
      // Y''={X'r1,Y'r1,X'r3,Y'r3}. (A0,B0)->(W0,W2); (A1,B1)->(W1,W3):
      // lane quad q ends with keys {8q..8q+7} = PV A-frag for m=l15.
      // s_nop guards: VALU-write -> cross-lane-read wait states are NOT
      // auto-inserted across inline-asm boundaries by LLVM.
      asm volatile("s_nop 1" ::: "memory"); // cvt_pk writes -> permlane reads
      asm("v_permlane32_swap_b32 %0, %1" : "+v"(wrd[0]), "+v"(wrd[2]));
      asm("v_permlane32_swap_b32 %0, %1" : "+v"(wrd[1]), "+v"(wrd[3]));
      asm volatile("s_nop 1" ::: "memory"); // permlane32 -> dependent permlane16
      asm("v_permlane16_swap_b32 %0, %1" : "+v"(wrd[0]), "+v"(wrd[2]));
      asm("v_permlane16_swap_b32 %0, %1" : "+v"(wrd[1]), "+v"(wrd[3]));
      asm volatile("s_nop 1" ::: "memory"); // permlane16 -> MFMA src read
      u32x4v pw_;
      pw_.x = wrd[0]; pw_.y = wrd[1]; pw_.z = wrd[2]; pw_.w = wrd[3];
      bf8v pf = __builtin_bit_cast(bf8v, pw_);
      // O_g += P_g @ V_half ; l_g += P_g @ ones.
      o_l[g] = __builtin_amdgcn_mfma_f32_16x16x32_bf16(pf, onesv, o_l[g], 0, 0, 0);
#pragma unroll
      for (int dt = 0; dt < 4; dt++)
        o[g][dt] = __builtin_amdgcn_mfma_f32_16x16x32_bf16(pf, vf[dt],
                                                           o[g][dt], 0, 0, 0);
    }
    __syncthreads(); // drains this iter's DMA (vmcnt) + frees cur buf
  }

  // ---- merge key halves. kh==1 waves publish (O,l); kh==0 combine+store.
  float* Of = (float*)smem;             // [128 q][66] f32 = 33792 B
  float* Lf = (float*)(smem + 16896);   // 128 f32
  if (kh == 1) {
#pragma unroll
    for (int g = 0; g < 2; g++)
#pragma unroll
      for (int r = 0; r < 4; r++) {
        int ql = qw * 32 + g * 16 + quad * 4 + r;
#pragma unroll
        for (int dt = 0; dt < 4; dt++)
          Of[ql * 66 + dt * 16 + l15] = o[g][dt][r];
        if (l15 == 0) Lf[ql] = o_l[g][r];
      }
  }
  __syncthreads();
  if (kh == 0) {
#pragma unroll
    for (int g = 0; g < 2; g++)
#pragma unroll
      for (int r = 0; r < 4; r++) {
        int ql = qw * 32 + g * 16 + quad * 4 + r;
        float linv = 1.0f / (o_l[g][r] + Lf[ql]);
        __bf16* orow =
            (__bf16*)(ctx + (size_t)(b * T_SEQ + q0 + ql) * D_MODEL + h * HDIM);
#pragma unroll
        for (int dt = 0; dt < 4; dt++)
          orow[dt * 16 + l15] =
              (__bf16)((o[g][dt][r] + Of[ql * 66 + dt * 16 + l15]) * linv);
      }
  }
}

// ---------------------------------------------------------------------------
extern "C" void kernel_launch(void* const* d_in, const int* in_sizes, int n_in,
                              void* d_out, int out_size, void* d_ws,
                              size_t ws_size, hipStream_t stream) {
  const float* q = (const float*)d_in[0];
  const float* k = (const float*)d_in[1];
  const float* v = (const float*)d_in[2];
  const float* frac = (const float*)d_in[3];
  const float* Wq = (const float*)d_in[4];
  const float* Wk = (const float*)d_in[5];
  const float* Wv = (const float*)d_in[6];
  const float* Wo = (const float*)d_in[7];
  const float* bq = (const float*)d_in[8];
  const float* bk = (const float*)d_in[9];
  const float* bv = (const float*)d_in[10];
  const float* bo = (const float*)d_in[11];
  const float* alpha_pos = (const float*)d_in[12];
  const float* alpha_neg = (const float*)d_in[13];

  char* ws = (char*)d_ws;
  u16* Xb = (u16*)(ws + 0);
  u16* Wt = (u16*)(ws + 25165824);
  u16* Qr = (u16*)(ws + 33554432);
  u16* Kr = (u16*)(ws + 41943040);
  u16* Vtmp = (u16*)(ws + 50331648); // holds ctx
  u16* Vb = (u16*)(ws + 58720256);
  float* ctab = (float*)(ws + 67108864);
  float* stab = (float*)(ws + 67371008);
  u16* ctx = Vtmp;
  u16* QKVout = Qr; // Qr,Kr contiguous; z==2 writes Vb directly

  k_prep<<<dim3(7424), 256, 0, stream>>>(q, k, v, Wq, Wk, Wv, Wo, Xb, Wt, ctab,
                                         stab);
  k_gemm_qkv<<<dim3(8, 32, 3), 256, 0, stream>>>(Xb, Wt, bq, bk, bv, ctab, stab,
                                                 QKVout, Vb);
  k_attn<<<dim3(16, 32), 512, 0, stream>>>(Qr, Kr, Vb, frac, alpha_pos,
                                           alpha_neg, ctx);
  k_gemm_out<<<dim3(16, 64), 256, 0, stream>>>(ctx, Wt + 3 * 1048576, bo,
                                               (float*)d_out);
}

// Round 10
// 219.904 us; speedup vs baseline: 1.0505x; 1.0505x over previous
//
#include <hip/hip_runtime.h>

// ---------------------------------------------------------------------------
// CustomMultiHeadAttentionStoich: fused MHA with RoPE + frac-difference bias.
// B=2 T=2048 D_MODEL=1024 H=16 hd=64. All matmuls via mfma_f32_16x16x32_bf16.
//
// Verified gfx950 fragment layouts (learn_hip m89/m91, rounds 1-6 pass):
//   A-frag : lane holds A[m=lane&15][k=(lane>>4)*8 + j], j=0..7  (8 bf16, 16B)
//   B-frag : lane holds B[k=(lane>>4)*8 + j][n=lane&15]
//   C/D    : lane holds D[row=(lane>>4)*4 + r][col=lane&15], r=0..3 (4 f32)
//
// Round-17: q-tile-64 attn failed 3x (R5/R6/R9, incl. with hazard guards)
// while q-tile-128 passed 3x (R3/R4/R8) -> that geometry is PERMANENTLY
// abandoned. R4-vs-R8 comparison shows gemm_out dbuf/single are within
// noise (my R4 attribution was wrong) and qkv still has headroom. This
// round: SAFE qkv occupancy upgrade.
//  * k_gemm_qkv: 256 -> 512 threads/block, same BM=BN=128 / BK=64 tile and
//    same 64KB dbuf LDS -> still 2 blocks/CU but 16 waves/CU (was 8).
//    Wave-tile 64x64 -> 32x64 (acc 64->32 VGPR). Staging: 4 gl2lds per
//    stage (vmcnt(4)); LDS layout and ALL fragment/epilogue formulas are
//    unchanged (rows 0-127 x stride-32 planes).
//  * k_attn / k_prep / k_gemm_out byte-identical to R8 (passing, 231.0us).
// ---------------------------------------------------------------------------

typedef unsigned short u16;
typedef __bf16 bf8v __attribute__((ext_vector_type(8)));
typedef __bf16 bf4v __attribute__((ext_vector_type(4)));
typedef float f32x4 __attribute__((ext_vector_type(4)));
typedef unsigned int u32x4v __attribute__((ext_vector_type(4)));

#define D_MODEL 1024
#define T_SEQ   2048
#define NHEAD   16
#define HDIM    64
#define BATCH   2
#define M_TOT   (BATCH * T_SEQ) /* 4096 */
#define LOG2E   1.4426950408889634f

__device__ __forceinline__ void gl2lds16(const u16* g, u16* l) {
  __builtin_amdgcn_global_load_lds(
      (__attribute__((address_space(1))) void*)g,
      (__attribute__((address_space(3))) void*)l, 16, 0, 0);
}

// ---------------------------------------------------------------------------
// k_prep: zone-partitioned prep work in ONE launch.
//   blocks [0,6144)    : f32->bf16 convert of q/k/v into Xb
//   blocks [6144,7168) : W^T bf16 transpose of Wq/Wk/Wv/Wo into WtB
//   blocks [7168,7424) : RoPE cos/sin table
__global__ __launch_bounds__(256) void k_prep(
    const float* __restrict__ q, const float* __restrict__ k,
    const float* __restrict__ v, const float* __restrict__ Wq,
    const float* __restrict__ Wk, const float* __restrict__ Wv,
    const float* __restrict__ Wo, u16* __restrict__ Xb, u16* __restrict__ WtB,
    float* __restrict__ ct, float* __restrict__ st) {
  __shared__ float tile[64 * 65];
  int bx = blockIdx.x, tid = threadIdx.x;
  if (bx < 6144) { // ---- convert zone
    int z = bx >> 11, xb = bx & 2047;
    const float* src = (z == 0) ? q : (z == 1) ? k : v;
    u16* dst = Xb + (size_t)z * (M_TOT * D_MODEL);
    int idx = (xb * 256 + tid) * 8;
    float4 a = *(const float4*)(src + idx);
    float4 b = *(const float4*)(src + idx + 4);
    bf8v o;
    o[0] = (__bf16)a.x; o[1] = (__bf16)a.y; o[2] = (__bf16)a.z; o[3] = (__bf16)a.w;
    o[4] = (__bf16)b.x; o[5] = (__bf16)b.y; o[6] = (__bf16)b.z; o[7] = (__bf16)b.w;
    *(bf8v*)(dst + idx) = o;
  } else if (bx < 7168) { // ---- W transpose zone (64x64 tiles, stride 65)
    int idx2 = bx - 6144;
    int z = idx2 >> 8, rem = idx2 & 255;
    int k0 = (rem >> 4) * 64, n0 = (rem & 15) * 64;
    const float* W = (z == 0) ? Wq : (z == 1) ? Wk : (z == 2) ? Wv : Wo;
    u16* Wt = WtB + (size_t)z * (D_MODEL * D_MODEL);
#pragma unroll
    for (int i = 0; i < 16; i++) {
      int idx = tid + i * 256;
      int r = idx >> 6, c = idx & 63;
      tile[c * 65 + r] = W[(size_t)(k0 + r) * D_MODEL + n0 + c];
    }
    __syncthreads();
#pragma unroll
    for (int i = 0; i < 16; i++) {
      int idx = tid + i * 256;
      int r = idx >> 6, c = idx & 63;
      ((__bf16*)Wt)[(size_t)(n0 + r) * D_MODEL + k0 + c] = (__bf16)tile[r * 65 + c];
    }
  } else { // ---- RoPE table zone: angle(t,d) = t / 10000^(d/32)
    int idx = (bx - 7168) * 256 + tid; // = t*32 + d
    int t = idx >> 5, d = idx & 31;
    float ang = (float)t * powf(10000.0f, -(float)d * (1.0f / 32.0f));
    ct[idx] = cosf(ang);
    st[idx] = sinf(ang);
  }
}

// ---------------------------------------------------------------------------
// QKV GEMM core v3 (512 thr / 8 waves): C = A[M][K] @ Bt[N][K]^T, K=1024,
// BK=64, BM=BN=128. Wave w: rows (w>>1)*32..+32, cols (w&1)*64..+64.
// DOUBLE-buffered global_load_lds staging with counted vmcnt:
//   per iter: B1(s_barrier) -> stage(t+1) (4 gl2lds) -> vmcnt(4)
//   (own stage(t) landed; stage(t+1) flying) -> B2(s_barrier) -> compute.
// LDS layout identical to the 256-thr version: per operand, plane kh
// (cols kh*32..+32) holds rows 0..127 at stride 32 elems.
// Staging map: thread t covers row t>>2, col-chunk (t&3)*8 of each plane;
// LDS chunk index = wave*64 + lane = t (linear, wave-uniform base).
__device__ __forceinline__ void gemm_core_128x512(const u16* __restrict__ A,
                                                  const u16* __restrict__ Bt,
                                                  u16* sA, u16* sB,
                                                  f32x4 (&acc)[2][4],
                                                  int m0, int n0) {
  const int K = D_MODEL;
  const int NT = K / 64; // 16
  int tid = threadIdx.x;
  int lane = tid & 63, wave = tid >> 6;
  int l15 = lane & 15, quad = lane >> 4;
  int wm = (wave >> 1) * 32, wn = (wave & 1) * 64;
  int r0 = tid >> 2, pcol0 = (tid & 3) * 8; // row 0..127, col-chunk 0..3
  const u16* A0 = A + (size_t)(m0 + r0) * K + pcol0;
  const u16* B0 = Bt + (size_t)(n0 + r0) * K + pcol0;
  u16* dA = sA + wave * 512; // wave-uniform base; lane -> +lane*8 elems
  u16* dB = sB + wave * 512;
  auto stg = [&](int bo, int k0) {
    gl2lds16(A0 + k0, dA + bo);            // A plane0 (cols k0..k0+31)
    gl2lds16(A0 + k0 + 32, dA + 4096 + bo); // A plane1
    gl2lds16(B0 + k0, dB + bo);            // B plane0
    gl2lds16(B0 + k0 + 32, dB + 4096 + bo); // B plane1
  };
  stg(0, 0);
  for (int t = 0; t < NT; t++) {
    int bo = (t & 1) * 8192;
    __builtin_amdgcn_s_barrier(); // B1: all waves done reading buf[t-1]
    if (t + 1 < NT) {
      stg(bo ^ 8192, (t + 1) * 64);
      asm volatile("s_waitcnt vmcnt(4)" ::: "memory"); // stage(t) landed
    } else {
      asm volatile("s_waitcnt vmcnt(0)" ::: "memory"); // last: drain
    }
    __builtin_amdgcn_s_barrier(); // B2: all waves' stage(t) landed
#pragma unroll
    for (int kh = 0; kh < 2; kh++) {
      bf8v af[2], bf[4];
#pragma unroll
      for (int i = 0; i < 2; i++)
        af[i] = *(const bf8v*)(sA + bo + kh * 4096 + (wm + i * 16 + l15) * 32 + quad * 8);
#pragma unroll
      for (int i = 0; i < 4; i++)
        bf[i] = *(const bf8v*)(sB + bo + kh * 4096 + (wn + i * 16 + l15) * 32 + quad * 8);
#pragma unroll
      for (int mi = 0; mi < 2; mi++)
#pragma unroll
        for (int ni = 0; ni < 4; ni++)
          acc[mi][ni] = __builtin_amdgcn_mfma_f32_16x16x32_bf16(
              af[mi], bf[ni], acc[mi][ni], 0, 0, 0);
    }
  }
}

// QKV projection, grid (8, 32, 3), 512 thr. XCD-swizzled: XCD = bx (lin%8);
// each XCD owns 4 consecutive m-panels x all 8 n-blocks -> A 1MB + B 2MB
// L2-resident. z<2 -> RoPE fused; z==0 prescales Q by 0.125*log2e. z==2
// writes projected V DIRECTLY TRANSPOSED into Vb[b][h][d][t].
__global__ __launch_bounds__(512, 2) void k_gemm_qkv(
    const u16* __restrict__ Xb, const u16* __restrict__ WtB,
    const float* __restrict__ bq, const float* __restrict__ bk,
    const float* __restrict__ bv, const float* __restrict__ ctab,
    const float* __restrict__ stab, u16* __restrict__ OutB,
    u16* __restrict__ Vb) {
  __shared__ __align__(16) u16 sA[2 * 128 * 64];
  __shared__ __align__(16) u16 sB[2 * 128 * 64];
  int z = blockIdx.z;
  const u16* A = Xb + (size_t)z * (M_TOT * D_MODEL);
  const u16* Bt = WtB + (size_t)z * (D_MODEL * D_MODEL);
  const float* bias = (z == 0) ? bq : (z == 1) ? bk : bv;
  u16* Out = OutB + (size_t)z * (M_TOT * D_MODEL);
  // XCD swizzle: xcd = blockIdx.x (grid x=8; lin%8 = bx since 8|8*by, 8|256*bz)
  int mblk = (blockIdx.x << 2) | (blockIdx.y >> 3);
  int nblk = blockIdx.y & 7;
  int m0 = mblk * 128, n0 = nblk * 128;
  f32x4 acc[2][4] = {};
  gemm_core_128x512(A, Bt, sA, sB, acc, m0, n0);

  int tid = threadIdx.x, lane = tid & 63, wave = tid >> 6;
  int l15 = lane & 15, quad = lane >> 4;
  int wm = (wave >> 1) * 32, wn = (wave & 1) * 64;
  float bvv[4];
#pragma unroll
  for (int ni = 0; ni < 4; ni++) bvv[ni] = bias[n0 + wn + ni * 16 + l15];

  if (z < 2) { // Q/K: RoPE fused; Q also prescaled 0.125*log2e
    float qs = (z == 0) ? 0.125f * LOG2E : 1.0f;
#pragma unroll
    for (int mi = 0; mi < 2; mi++) {
#pragma unroll
      for (int r = 0; r < 4; r++) {
        int m = m0 + wm + mi * 16 + quad * 4 + r; // global row = b*T + t
        size_t ro = (size_t)m * D_MODEL + n0 + wn;
        int tl = m & (T_SEQ - 1);
#pragma unroll
        for (int ni = 0; ni < 2; ni++) {
          int d = ni * 16 + l15; // < 32; pair (d, d+32) in regs ni, ni+2
          float c = ctab[tl * 32 + d], s = stab[tl * 32 + d];
          float xl = acc[mi][ni][r] + bvv[ni];
          float xr = acc[mi][ni + 2][r] + bvv[ni + 2];
          ((__bf16*)Out)[ro + d] = (__bf16)((xl * c - xr * s) * qs);
          ((__bf16*)Out)[ro + d + 32] = (__bf16)((xl * s + xr * c) * qs);
        }
      }
    }
  } else { // V: write transposed Vb[b][h][d][t] (wave's 64 cols = one head)
    int hh = (n0 + wn) >> 6;
    int mbase = m0 + wm;
    int bb = mbase >> 11; // tile never crosses batch (2048 % 128 == 0)
    int tbase = mbase & (T_SEQ - 1);
    u16* Vw = Vb + (size_t)(bb * NHEAD + hh) * HDIM * T_SEQ;
#pragma unroll
    for (int mi = 0; mi < 2; mi++)
#pragma unroll
      for (int r = 0; r < 4; r++) {
        int t = tbase + mi * 16 + quad * 4 + r;
#pragma unroll
        for (int ni = 0; ni < 4; ni++) {
          int d = ni * 16 + l15;
          ((__bf16*)Vw)[(size_t)d * T_SEQ + t] = (__bf16)(acc[mi][ni][r] + bvv[ni]);
        }
      }
  }
}

// Output projection: ctx bf16 @ Wo^T + bo -> f32 d_out. 64x64 tiles, grid
// (16, 64) = 1024 blocks, XCD-swizzled (8 m-panels x 16 n per XCD: A 1MB +
// B 2MB L2-resident). Double-buffered staging with counted vmcnt(4).
__global__ __launch_bounds__(256) void k_gemm_out(
    const u16* __restrict__ ctx, const u16* __restrict__ Wot,
    const float* __restrict__ bo, float* __restrict__ Cout) {
  __shared__ __align__(16) u16 sA[2 * 64 * 64];
  __shared__ __align__(16) u16 sB[2 * 64 * 64];
  const int K = D_MODEL;
  const int NT = K / 64; // 16
  // XCD swizzle: lin = bx + 16*by -> xcd = bx&7. Per-xcd slot: (bx>>3)*64+by.
  int xcd = blockIdx.x & 7;
  int idx = ((blockIdx.x >> 3) << 6) | blockIdx.y; // 0..127
  int m0 = (xcd * 8 + (idx >> 4)) * 64;
  int n0 = (idx & 15) * 64;
  int tid = threadIdx.x, lane = tid & 63, wave = tid >> 6;
  int l15 = lane & 15, quad = lane >> 4;
  int wm = (wave >> 1) * 32, wn = (wave & 1) * 32;
  int r0 = tid >> 2, pcol0 = (tid & 3) * 8;
  const u16* A0 = ctx + (size_t)(m0 + r0) * K + pcol0;
  const u16* B0 = Wot + (size_t)(n0 + r0) * K + pcol0;
  u16* dA = sA + wave * 512; // one call = one full 64x32 plane (256 thr)
  u16* dB = sB + wave * 512;
  auto stg = [&](int bo, int k0) {
    gl2lds16(A0 + k0, dA + bo);
    gl2lds16(A0 + k0 + 32, dA + 2048 + bo); // plane1
    gl2lds16(B0 + k0, dB + bo);
    gl2lds16(B0 + k0 + 32, dB + 2048 + bo);
  };
  f32x4 acc[2][2] = {};
  stg(0, 0);
  for (int t = 0; t < NT; t++) {
    int bo = (t & 1) * 4096;
    __builtin_amdgcn_s_barrier(); // B1: all waves done reading buf[t-1]
    if (t + 1 < NT) {
      stg(bo ^ 4096, (t + 1) * 64);
      asm volatile("s_waitcnt vmcnt(4)" ::: "memory"); // stage(t) landed
    } else {
      asm volatile("s_waitcnt vmcnt(0)" ::: "memory");
    }
    __builtin_amdgcn_s_barrier(); // B2: all waves' stage(t) landed
#pragma unroll
    for (int kh = 0; kh < 2; kh++) {
      bf8v af[2], bf[2];
#pragma unroll
      for (int i = 0; i < 2; i++)
        af[i] = *(const bf8v*)(sA + bo + kh * 2048 + (wm + i * 16 + l15) * 32 + quad * 8);
#pragma unroll
      for (int i = 0; i < 2; i++)
        bf[i] = *(const bf8v*)(sB + bo + kh * 2048 + (wn + i * 16 + l15) * 32 + quad * 8);
#pragma unroll
      for (int mi = 0; mi < 2; mi++)
#pragma unroll
        for (int ni = 0; ni < 2; ni++)
          acc[mi][ni] = __builtin_amdgcn_mfma_f32_16x16x32_bf16(
              af[mi], bf[ni], acc[mi][ni], 0, 0, 0);
    }
  }
  float bvv[2];
#pragma unroll
  for (int ni = 0; ni < 2; ni++) bvv[ni] = bo[n0 + wn + ni * 16 + l15];
#pragma unroll
  for (int mi = 0; mi < 2; mi++)
#pragma unroll
    for (int r = 0; r < 4; r++) {
      size_t ro = (size_t)(m0 + wm + mi * 16 + quad * 4 + r) * D_MODEL + n0 + wn;
#pragma unroll
      for (int ni = 0; ni < 2; ni++)
        Cout[ro + ni * 16 + l15] = acc[mi][ni][r] + bvv[ni];
    }
}

// ---------------------------------------------------------------------------
// Flash attention v10h (R8-exact, PASSING): grid (T/128, B*H) XCD-swizzled,
// 512 thr = 8 waves. Wave w: q sub-tile qw = w&3 (32 rows), key half
// kh = w>>2. exp2-native softmax without max-subtraction => key halves
// accumulate independent unnormalized (O, l), merged once at the end via
// LDS. K/V double-buffered global_load_lds DMA, ONE __syncthreads per tile.
// P transpose IN-REGISTER (cvt_pk + permlane swaps) with EXPLICIT s_nop
// wait-states (LLVM does not insert hazard nops across inline-asm
// boundaries; VALU-write -> cross-lane-read needs wait states).
__global__ __launch_bounds__(512, 4) void k_attn(
    const u16* __restrict__ Qr, const u16* __restrict__ Kr,
    const u16* __restrict__ Vb, const float* __restrict__ frac,
    const float* __restrict__ alpha_pos, const float* __restrict__ alpha_neg,
    u16* __restrict__ ctx) {
  // smem carve (u16 elems):
  //   [0,8192)       kT[2][4096]  swizzled [key][d]
  //   [8192,16384)   vT[2][4096]  swizzled [d][key]
  //   [16384,20480)  fLds: f32[2048] frac row for this batch
  // merge phase reuses [0,16896) as f32 O-scratch, [16896,17152) l-scratch.
  __shared__ __align__(16) u16 smem[20480];
  // ---- XCD swizzle: lin%8 = XCD (round-robin). Give each XCD 4 whole heads
  // so all 16 q-blocks of a head share one L2 (K/V single-fetch per XCD).
  int lin = blockIdx.x + (blockIdx.y << 4);
  int xcd = lin & 7, slot = lin >> 3;
  int bh = (xcd << 2) | (slot >> 4);
  int q0 = (slot & 15) << 7;
  int b = bh >> 4, h = bh & 15;
  int tid = threadIdx.x, wave = tid >> 6, lane = tid & 63;
  int l15 = lane & 15, quad = lane >> 4;
  int qw = wave & 3;  // q sub-tile (32 rows)
  int kh = wave >> 2; // key half within each 64-key tile

  const u16* Kh = Kr + (size_t)b * T_SEQ * D_MODEL + h * HDIM;
  const u16* Vh = Vb + (size_t)bh * HDIM * T_SEQ;
  const float* fb = frac + b * T_SEQ;

  u16* kT0 = smem;
  u16* vT0 = smem + 8192;
  float* fl = (float*)(smem + 16384);

  // Q B-frags (B[k=d][n=q] = Q[q][d]): lane holds Q[q=l15][d=quad*8+j]
  bf8v qf[2][2];
  float fq[2];
#pragma unroll
  for (int g = 0; g < 2; g++) {
    int qrow = q0 + qw * 32 + g * 16 + l15;
    const u16* qbase =
        Qr + (size_t)(b * T_SEQ + qrow) * D_MODEL + h * HDIM + quad * 8;
    qf[g][0] = *(const bf8v*)qbase;
    qf[g][1] = *(const bf8v*)(qbase + 32);
    fq[g] = fb[qrow]; // S^T col = q = l15
  }
  // frac -> LDS (512 thr x 4 floats = 2048)
  {
    f32x4 fv = *(const f32x4*)(fb + (tid << 2));
    *(f32x4*)(fl + (tid << 2)) = fv;
  }

  // bias = ap*max(dd,0)+an*min(dd,0) = c1*dd + c2*|dd| (log2 domain)
  float ap = alpha_pos[h] * LOG2E, an = alpha_neg[h] * LOG2E;
  float c1 = 0.5f * (ap + an), c2 = 0.5f * (ap - an);
  bf8v onesv;
#pragma unroll
  for (int j = 0; j < 8; j++) onesv[j] = (__bf16)1.0f;
  f32x4 zero4 = {};
  f32x4 o[2][4] = {};
  f32x4 o_l[2] = {};

  // Hoisted frag offsets (elems). Swizzle: row r, chunk gc -> pc = gc^(r&7).
  int x0 = (quad ^ (l15 & 7)) * 8;
  int kidx[2], vidx[4];
#pragma unroll
  for (int nt = 0; nt < 2; nt++) // K rows kh*32 + nt*16 + l15
    kidx[nt] = (((kh * 2 + nt) * 16 + l15) << 6) + x0;
#pragma unroll
  for (int dt = 0; dt < 4; dt++) // V keys chunk quad + kh*4
    vidx[dt] = (((dt * 16 + l15) << 6) + x0) ^ (kh * 32);

  // DMA staging map: 512 threads x 1 chunk per array per tile.
  // chunk p = tid; row = p>>3, pc = p&7; fetch global chunk gc = pc^(row&7).
  int kr0 = tid >> 3, gc0 = (tid & 7) ^ (kr0 & 7);
  const u16* kg0 = Kh + (size_t)kr0 * D_MODEL + gc0 * 8;
  const u16* vg0 = Vh + (size_t)kr0 * T_SEQ + gc0 * 8; // row = d here
  int woff = wave * 512; // wave-uniform LDS dest (elems); lane -> +lane*8

  auto stage = [&](int bufoff, int kbase) {
    gl2lds16(kg0 + (size_t)kbase * D_MODEL, kT0 + bufoff + woff);
    gl2lds16(vg0 + kbase, vT0 + bufoff + woff);
  };

  stage(0, 0);
  __syncthreads(); // DMA + frac-LDS visible

#pragma unroll 2
  for (int kt = 0; kt < T_SEQ / 64; kt++) {
    int kbase = kt * 64;
    int bo = (kt & 1) * 4096;
    if (kt + 1 < T_SEQ / 64) stage(bo ^ 4096, kbase + 64);
    const u16* kb = kT0 + bo;
    const u16* vb = vT0 + bo;

    // K A-frags for this wave's key half: rows kh*32 + nt*16 + l15
    bf8v kf0[2], kf1[2];
#pragma unroll
    for (int nt = 0; nt < 2; nt++) {
      kf0[nt] = *(const bf8v*)(kb + kidx[nt]);
      kf1[nt] = *(const bf8v*)(kb + (kidx[nt] ^ 32));
    }
    // V B-frags: rows d = dt*16+l15; key chunks kh*4 + quad
    bf8v vf[4];
#pragma unroll
    for (int dt = 0; dt < 4; dt++) vf[dt] = *(const bf8v*)(vb + vidx[dt]);
    // frac[key] for this lane's 4 keys per nt (LDS, 16-lane broadcast)
    f32x4 fk4[2];
#pragma unroll
    for (int nt = 0; nt < 2; nt++)
      fk4[nt] = *(const f32x4*)(fl + kbase + kh * 32 + nt * 16 + quad * 4);

#pragma unroll
    for (int g = 0; g < 2; g++) {
      float fqg = fq[g];
      // wrd = [A0, A1, B0, B1]: A_m from nt0 keys {4q+2m,+1}, B_m from nt1.
      unsigned int wrd[4];
#pragma unroll
      for (int nt = 0; nt < 2; nt++) {
        // S^T tile: D[row=key_loc=nt*16+quad*4+r][col=q=l15], log2 domain
        f32x4 s = zero4;
        s = __builtin_amdgcn_mfma_f32_16x16x32_bf16(kf0[nt], qf[g][0], s, 0, 0, 0);
        s = __builtin_amdgcn_mfma_f32_16x16x32_bf16(kf1[nt], qf[g][1], s, 0, 0, 0);
        float p[4];
#pragma unroll
        for (int r = 0; r < 4; r++) {
          float dd = fk4[nt][r] - fqg;
          p[r] = __builtin_amdgcn_exp2f(
              fmaf(c2, __builtin_fabsf(dd), fmaf(c1, dd, s[r])));
        }
        unsigned int w0, w1;
        asm("v_cvt_pk_bf16_f32 %0, %1, %2" : "=v"(w0) : "v"(p[0]), "v"(p[1]));
        asm("v_cvt_pk_bf16_f32 %0, %1, %2" : "=v"(w1) : "v"(p[2]), "v"(p[3]));
        wrd[nt * 2 + 0] = w0;
        wrd[nt * 2 + 1] = w1;
      }
      // In-register P transpose. permlane32_swap: X'={Xq0,Xq1,Yq0,Yq1},
      // Y'={Xq2,Xq3,Yq2,Yq3}. permlane16_swap: X''={X'r0,Y'r0,X'r2,Y'r2},
      // Y''={X'r1,Y'r1,X'r3,Y'r3}. (A0,B0)->(W0,W2); (A1,B1)->(W1,W3):
      // lane quad q ends with keys {8q..8q+7} = PV A-frag for m=l15.
      // s_nop guards: VALU-write -> cross-lane-read wait states are NOT
      // auto-inserted across inline-asm boundaries by LLVM (R7/R8-proven).
      asm volatile("s_nop 1" ::: "memory"); // cvt_pk writes -> permlane reads
      asm("v_permlane32_swap_b32 %0, %1" : "+v"(wrd[0]), "+v"(wrd[2]));
      asm("v_permlane32_swap_b32 %0, %1" : "+v"(wrd[1]), "+v"(wrd[3]));
      asm volatile("s_nop 1" ::: "memory"); // permlane32 -> dependent permlane16
      asm("v_permlane16_swap_b32 %0, %1" : "+v"(wrd[0]), "+v"(wrd[2]));
      asm("v_permlane16_swap_b32 %0, %1" : "+v"(wrd[1]), "+v"(wrd[3]));
      asm volatile("s_nop 1" ::: "memory"); // permlane16 -> MFMA src read
      u32x4v pw_;
      pw_.x = wrd[0]; pw_.y = wrd[1]; pw_.z = wrd[2]; pw_.w = wrd[3];
      bf8v pf = __builtin_bit_cast(bf8v, pw_);
      // O_g += P_g @ V_half ; l_g += P_g @ ones.
      o_l[g] = __builtin_amdgcn_mfma_f32_16x16x32_bf16(pf, onesv, o_l[g], 0, 0, 0);
#pragma unroll
      for (int dt = 0; dt < 4; dt++)
        o[g][dt] = __builtin_amdgcn_mfma_f32_16x16x32_bf16(pf, vf[dt],
                                                           o[g][dt], 0, 0, 0);
    }
    __syncthreads(); // drains this iter's DMA (vmcnt) + frees cur buf
  }

  // ---- merge key halves. kh==1 waves publish (O,l); kh==0 combine+store.
  float* Of = (float*)smem;             // [128 q][66] f32 = 33792 B
  float* Lf = (float*)(smem + 16896);   // 128 f32
  if (kh == 1) {
#pragma unroll
    for (int g = 0; g < 2; g++)
#pragma unroll
      for (int r = 0; r < 4; r++) {
        int ql = qw * 32 + g * 16 + quad * 4 + r;
#pragma unroll
        for (int dt = 0; dt < 4; dt++)
          Of[ql * 66 + dt * 16 + l15] = o[g][dt][r];
        if (l15 == 0) Lf[ql] = o_l[g][r];
      }
  }
  __syncthreads();
  if (kh == 0) {
#pragma unroll
    for (int g = 0; g < 2; g++)
#pragma unroll
      for (int r = 0; r < 4; r++) {
        int ql = qw * 32 + g * 16 + quad * 4 + r;
        float linv = 1.0f / (o_l[g][r] + Lf[ql]);
        __bf16* orow =
            (__bf16*)(ctx + (size_t)(b * T_SEQ + q0 + ql) * D_MODEL + h * HDIM);
#pragma unroll
        for (int dt = 0; dt < 4; dt++)
          orow[dt * 16 + l15] =
              (__bf16)((o[g][dt][r] + Of[ql * 66 + dt * 16 + l15]) * linv);
      }
  }
}

// ---------------------------------------------------------------------------
extern "C" void kernel_launch(void* const* d_in, const int* in_sizes, int n_in,
                              void* d_out, int out_size, void* d_ws,
                              size_t ws_size, hipStream_t stream) {
  const float* q = (const float*)d_in[0];
  const float* k = (const float*)d_in[1];
  const float* v = (const float*)d_in[2];
  const float* frac = (const float*)d_in[3];
  const float* Wq = (const float*)d_in[4];
  const float* Wk = (const float*)d_in[5];
  const float* Wv = (const float*)d_in[6];
  const float* Wo = (const float*)d_in[7];
  const float* bq = (const float*)d_in[8];
  const float* bk = (const float*)d_in[9];
  const float* bv = (const float*)d_in[10];
  const float* bo = (const float*)d_in[11];
  const float* alpha_pos = (const float*)d_in[12];
  const float* alpha_neg = (const float*)d_in[13];

  char* ws = (char*)d_ws;
  u16* Xb = (u16*)(ws + 0);
  u16* Wt = (u16*)(ws + 25165824);
  u16* Qr = (u16*)(ws + 33554432);
  u16* Kr = (u16*)(ws + 41943040);
  u16* Vtmp = (u16*)(ws + 50331648); // holds ctx
  u16* Vb = (u16*)(ws + 58720256);
  float* ctab = (float*)(ws + 67108864);
  float* stab = (float*)(ws + 67371008);
  u16* ctx = Vtmp;
  u16* QKVout = Qr; // Qr,Kr contiguous; z==2 writes Vb directly

  k_prep<<<dim3(7424), 256, 0, stream>>>(q, k, v, Wq, Wk, Wv, Wo, Xb, Wt, ctab,
                                         stab);
  k_gemm_qkv<<<dim3(8, 32, 3), 512, 0, stream>>>(Xb, Wt, bq, bk, bv, ctab, stab,
                                                 QKVout, Vb);
  k_attn<<<dim3(16, 32), 512, 0, stream>>>(Qr, Kr, Vb, frac, alpha_pos,
                                           alpha_neg, ctx);
  k_gemm_out<<<dim3(16, 64), 256, 0, stream>>>(ctx, Wt + 3 * 1048576, bo,
                                               (float*)d_out);
}

// Round 11
// 218.549 us; speedup vs baseline: 1.0570x; 1.0062x over previous
//
#include <hip/hip_runtime.h>

// ---------------------------------------------------------------------------
// CustomMultiHeadAttentionStoich: fused MHA with RoPE + frac-difference bias.
// B=2 T=2048 D_MODEL=1024 H=16 hd=64. All matmuls via mfma_f32_16x16x32_bf16.
//
// Verified gfx950 fragment layouts (learn_hip m89/m91, rounds 1-6 pass):
//   A-frag : lane holds A[m=lane&15][k=(lane>>4)*8 + j], j=0..7  (8 bf16, 16B)
//   B-frag : lane holds B[k=(lane>>4)*8 + j][n=lane&15]
//   C/D    : lane holds D[row=(lane>>4)*4 + r][col=lane&15], r=0..3 (4 f32)
//
// Round-18: R10 passed (219.9us; qkv 512-thr +11us as predicted). k_attn
// (55us) is the only top-5 kernel; the bigger pool is prep/qkv/out. This
// round: k_gemm_out restructure composing two session-proven patterns:
//  * R10 qkv structure: 512 thr, dbuf LDS, counted vmcnt + raw s_barrier.
//  * attn's XOR-chunk swizzle (phys = gc^(row&7), proven in kT/vT): each
//    operand stored as ONE swizzled [64][64] tile -> one gl2lds per operand
//    per K-step (512 x 16B = 8KB exact). Stage = 2 ops -> vmcnt(2); frag
//    reads 2 lanes/bank (free, m136). Algebra: phys chunk for (kh,quad) at
//    row r = (kh*4+quad)^(r&7), and elem-index form (idx)^(kh*32) holds.
//  LDS 32KB dbuf, 1024 blocks = exactly 4 blocks/CU x 8 waves = 32 waves/CU
//  (HW cap, zero tail). acc 8 VGPR/wave. Same grid + XCD swizzle as R10.
//  k_prep / k_gemm_qkv / k_attn byte-identical to R10 (passing).
// ---------------------------------------------------------------------------

typedef unsigned short u16;
typedef __bf16 bf8v __attribute__((ext_vector_type(8)));
typedef __bf16 bf4v __attribute__((ext_vector_type(4)));
typedef float f32x4 __attribute__((ext_vector_type(4)));
typedef unsigned int u32x4v __attribute__((ext_vector_type(4)));

#define D_MODEL 1024
#define T_SEQ   2048
#define NHEAD   16
#define HDIM    64
#define BATCH   2
#define M_TOT   (BATCH * T_SEQ) /* 4096 */
#define LOG2E   1.4426950408889634f

__device__ __forceinline__ void gl2lds16(const u16* g, u16* l) {
  __builtin_amdgcn_global_load_lds(
      (__attribute__((address_space(1))) void*)g,
      (__attribute__((address_space(3))) void*)l, 16, 0, 0);
}

// ---------------------------------------------------------------------------
// k_prep: zone-partitioned prep work in ONE launch.
//   blocks [0,6144)    : f32->bf16 convert of q/k/v into Xb
//   blocks [6144,7168) : W^T bf16 transpose of Wq/Wk/Wv/Wo into WtB
//   blocks [7168,7424) : RoPE cos/sin table
__global__ __launch_bounds__(256) void k_prep(
    const float* __restrict__ q, const float* __restrict__ k,
    const float* __restrict__ v, const float* __restrict__ Wq,
    const float* __restrict__ Wk, const float* __restrict__ Wv,
    const float* __restrict__ Wo, u16* __restrict__ Xb, u16* __restrict__ WtB,
    float* __restrict__ ct, float* __restrict__ st) {
  __shared__ float tile[64 * 65];
  int bx = blockIdx.x, tid = threadIdx.x;
  if (bx < 6144) { // ---- convert zone
    int z = bx >> 11, xb = bx & 2047;
    const float* src = (z == 0) ? q : (z == 1) ? k : v;
    u16* dst = Xb + (size_t)z * (M_TOT * D_MODEL);
    int idx = (xb * 256 + tid) * 8;
    float4 a = *(const float4*)(src + idx);
    float4 b = *(const float4*)(src + idx + 4);
    bf8v o;
    o[0] = (__bf16)a.x; o[1] = (__bf16)a.y; o[2] = (__bf16)a.z; o[3] = (__bf16)a.w;
    o[4] = (__bf16)b.x; o[5] = (__bf16)b.y; o[6] = (__bf16)b.z; o[7] = (__bf16)b.w;
    *(bf8v*)(dst + idx) = o;
  } else if (bx < 7168) { // ---- W transpose zone (64x64 tiles, stride 65)
    int idx2 = bx - 6144;
    int z = idx2 >> 8, rem = idx2 & 255;
    int k0 = (rem >> 4) * 64, n0 = (rem & 15) * 64;
    const float* W = (z == 0) ? Wq : (z == 1) ? Wk : (z == 2) ? Wv : Wo;
    u16* Wt = WtB + (size_t)z * (D_MODEL * D_MODEL);
#pragma unroll
    for (int i = 0; i < 16; i++) {
      int idx = tid + i * 256;
      int r = idx >> 6, c = idx & 63;
      tile[c * 65 + r] = W[(size_t)(k0 + r) * D_MODEL + n0 + c];
    }
    __syncthreads();
#pragma unroll
    for (int i = 0; i < 16; i++) {
      int idx = tid + i * 256;
      int r = idx >> 6, c = idx & 63;
      ((__bf16*)Wt)[(size_t)(n0 + r) * D_MODEL + k0 + c] = (__bf16)tile[r * 65 + c];
    }
  } else { // ---- RoPE table zone: angle(t,d) = t / 10000^(d/32)
    int idx = (bx - 7168) * 256 + tid; // = t*32 + d
    int t = idx >> 5, d = idx & 31;
    float ang = (float)t * powf(10000.0f, -(float)d * (1.0f / 32.0f));
    ct[idx] = cosf(ang);
    st[idx] = sinf(ang);
  }
}

// ---------------------------------------------------------------------------
// QKV GEMM core v3 (512 thr / 8 waves): C = A[M][K] @ Bt[N][K]^T, K=1024,
// BK=64, BM=BN=128. Wave w: rows (w>>1)*32..+32, cols (w&1)*64..+64.
// DOUBLE-buffered global_load_lds staging with counted vmcnt:
//   per iter: B1(s_barrier) -> stage(t+1) (4 gl2lds) -> vmcnt(4)
//   (own stage(t) landed; stage(t+1) flying) -> B2(s_barrier) -> compute.
// LDS layout identical to the 256-thr version: per operand, plane kh
// (cols kh*32..+32) holds rows 0..127 at stride 32 elems.
// Staging map: thread t covers row t>>2, col-chunk (t&3)*8 of each plane;
// LDS chunk index = wave*64 + lane = t (linear, wave-uniform base).
__device__ __forceinline__ void gemm_core_128x512(const u16* __restrict__ A,
                                                  const u16* __restrict__ Bt,
                                                  u16* sA, u16* sB,
                                                  f32x4 (&acc)[2][4],
                                                  int m0, int n0) {
  const int K = D_MODEL;
  const int NT = K / 64; // 16
  int tid = threadIdx.x;
  int lane = tid & 63, wave = tid >> 6;
  int l15 = lane & 15, quad = lane >> 4;
  int wm = (wave >> 1) * 32, wn = (wave & 1) * 64;
  int r0 = tid >> 2, pcol0 = (tid & 3) * 8; // row 0..127, col-chunk 0..3
  const u16* A0 = A + (size_t)(m0 + r0) * K + pcol0;
  const u16* B0 = Bt + (size_t)(n0 + r0) * K + pcol0;
  u16* dA = sA + wave * 512; // wave-uniform base; lane -> +lane*8 elems
  u16* dB = sB + wave * 512;
  auto stg = [&](int bo, int k0) {
    gl2lds16(A0 + k0, dA + bo);            // A plane0 (cols k0..k0+31)
    gl2lds16(A0 + k0 + 32, dA + 4096 + bo); // A plane1
    gl2lds16(B0 + k0, dB + bo);            // B plane0
    gl2lds16(B0 + k0 + 32, dB + 4096 + bo); // B plane1
  };
  stg(0, 0);
  for (int t = 0; t < NT; t++) {
    int bo = (t & 1) * 8192;
    __builtin_amdgcn_s_barrier(); // B1: all waves done reading buf[t-1]
    if (t + 1 < NT) {
      stg(bo ^ 8192, (t + 1) * 64);
      asm volatile("s_waitcnt vmcnt(4)" ::: "memory"); // stage(t) landed
    } else {
      asm volatile("s_waitcnt vmcnt(0)" ::: "memory"); // last: drain
    }
    __builtin_amdgcn_s_barrier(); // B2: all waves' stage(t) landed
#pragma unroll
    for (int kh = 0; kh < 2; kh++) {
      bf8v af[2], bf[4];
#pragma unroll
      for (int i = 0; i < 2; i++)
        af[i] = *(const bf8v*)(sA + bo + kh * 4096 + (wm + i * 16 + l15) * 32 + quad * 8);
#pragma unroll
      for (int i = 0; i < 4; i++)
        bf[i] = *(const bf8v*)(sB + bo + kh * 4096 + (wn + i * 16 + l15) * 32 + quad * 8);
#pragma unroll
      for (int mi = 0; mi < 2; mi++)
#pragma unroll
        for (int ni = 0; ni < 4; ni++)
          acc[mi][ni] = __builtin_amdgcn_mfma_f32_16x16x32_bf16(
              af[mi], bf[ni], acc[mi][ni], 0, 0, 0);
    }
  }
}

// QKV projection, grid (8, 32, 3), 512 thr. XCD-swizzled: XCD = bx (lin%8);
// each XCD owns 4 consecutive m-panels x all 8 n-blocks -> A 1MB + B 2MB
// L2-resident. z<2 -> RoPE fused; z==0 prescales Q by 0.125*log2e. z==2
// writes projected V DIRECTLY TRANSPOSED into Vb[b][h][d][t].
__global__ __launch_bounds__(512, 2) void k_gemm_qkv(
    const u16* __restrict__ Xb, const u16* __restrict__ WtB,
    const float* __restrict__ bq, const float* __restrict__ bk,
    const float* __restrict__ bv, const float* __restrict__ ctab,
    const float* __restrict__ stab, u16* __restrict__ OutB,
    u16* __restrict__ Vb) {
  __shared__ __align__(16) u16 sA[2 * 128 * 64];
  __shared__ __align__(16) u16 sB[2 * 128 * 64];
  int z = blockIdx.z;
  const u16* A = Xb + (size_t)z * (M_TOT * D_MODEL);
  const u16* Bt = WtB + (size_t)z * (D_MODEL * D_MODEL);
  const float* bias = (z == 0) ? bq : (z == 1) ? bk : bv;
  u16* Out = OutB + (size_t)z * (M_TOT * D_MODEL);
  // XCD swizzle: xcd = blockIdx.x (grid x=8; lin%8 = bx since 8|8*by, 8|256*bz)
  int mblk = (blockIdx.x << 2) | (blockIdx.y >> 3);
  int nblk = blockIdx.y & 7;
  int m0 = mblk * 128, n0 = nblk * 128;
  f32x4 acc[2][4] = {};
  gemm_core_128x512(A, Bt, sA, sB, acc, m0, n0);

  int tid = threadIdx.x, lane = tid & 63, wave = tid >> 6;
  int l15 = lane & 15, quad = lane >> 4;
  int wm = (wave >> 1) * 32, wn = (wave & 1) * 64;
  float bvv[4];
#pragma unroll
  for (int ni = 0; ni < 4; ni++) bvv[ni] = bias[n0 + wn + ni * 16 + l15];

  if (z < 2) { // Q/K: RoPE fused; Q also prescaled 0.125*log2e
    float qs = (z == 0) ? 0.125f * LOG2E : 1.0f;
#pragma unroll
    for (int mi = 0; mi < 2; mi++) {
#pragma unroll
      for (int r = 0; r < 4; r++) {
        int m = m0 + wm + mi * 16 + quad * 4 + r; // global row = b*T + t
        size_t ro = (size_t)m * D_MODEL + n0 + wn;
        int tl = m & (T_SEQ - 1);
#pragma unroll
        for (int ni = 0; ni < 2; ni++) {
          int d = ni * 16 + l15; // < 32; pair (d, d+32) in regs ni, ni+2
          float c = ctab[tl * 32 + d], s = stab[tl * 32 + d];
          float xl = acc[mi][ni][r] + bvv[ni];
          float xr = acc[mi][ni + 2][r] + bvv[ni + 2];
          ((__bf16*)Out)[ro + d] = (__bf16)((xl * c - xr * s) * qs);
          ((__bf16*)Out)[ro + d + 32] = (__bf16)((xl * s + xr * c) * qs);
        }
      }
    }
  } else { // V: write transposed Vb[b][h][d][t] (wave's 64 cols = one head)
    int hh = (n0 + wn) >> 6;
    int mbase = m0 + wm;
    int bb = mbase >> 11; // tile never crosses batch (2048 % 128 == 0)
    int tbase = mbase & (T_SEQ - 1);
    u16* Vw = Vb + (size_t)(bb * NHEAD + hh) * HDIM * T_SEQ;
#pragma unroll
    for (int mi = 0; mi < 2; mi++)
#pragma unroll
      for (int r = 0; r < 4; r++) {
        int t = tbase + mi * 16 + quad * 4 + r;
#pragma unroll
        for (int ni = 0; ni < 4; ni++) {
          int d = ni * 16 + l15;
          ((__bf16*)Vw)[(size_t)d * T_SEQ + t] = (__bf16)(acc[mi][ni][r] + bvv[ni]);
        }
      }
  }
}

// Output projection v2: ctx bf16 @ Wo^T + bo -> f32 d_out. 64x64 tiles,
// grid (16, 64) = 1024 blocks XCD-swizzled, 512 thr = 8 waves -> exactly
// 4 blocks/CU = 32 waves/CU (HW cap, zero tail; LDS 32KB dbuf).
// Each operand is ONE swizzled [64][64] tile per K-step: staging thread t
// covers row t>>3, phys chunk t&7, fetching global chunk (t&7)^(row&7) --
// one gl2lds per operand (512 x 16B = 8KB). Stage = 2 ops -> vmcnt(2).
// Frag read at row r, logical chunk c reads phys c^(r&7): elem-index form
// (row*64 + (quad^(r&7))*8) ^ (kh*32). 2 lanes/bank = conflict-free.
// Wave-tile 16x32: wm = (w&3)*16, wn = (w>>2)*32.
__global__ __launch_bounds__(512, 4) void k_gemm_out(
    const u16* __restrict__ ctx, const u16* __restrict__ Wot,
    const float* __restrict__ bo, float* __restrict__ Cout) {
  __shared__ __align__(16) u16 sA[2 * 64 * 64];
  __shared__ __align__(16) u16 sB[2 * 64 * 64];
  const int K = D_MODEL;
  const int NT = K / 64; // 16
  // XCD swizzle: lin = bx + 16*by -> xcd = bx&7. Per-xcd slot: (bx>>3)*64+by.
  int xcd = blockIdx.x & 7;
  int idx = ((blockIdx.x >> 3) << 6) | blockIdx.y; // 0..127
  int m0 = (xcd * 8 + (idx >> 4)) * 64;
  int n0 = (idx & 15) * 64;
  int tid = threadIdx.x, lane = tid & 63, wave = tid >> 6;
  int l15 = lane & 15, quad = lane >> 4;
  int wm = (wave & 3) * 16, wn = (wave >> 2) * 32;
  // Staging map: row r0 = tid>>3, phys chunk tid&7 -> global chunk gc0.
  int r0 = tid >> 3, gc0 = (tid & 7) ^ (r0 & 7);
  const u16* A0 = ctx + (size_t)(m0 + r0) * K + gc0 * 8;
  const u16* B0 = Wot + (size_t)(n0 + r0) * K + gc0 * 8;
  u16* dA = sA + wave * 512; // wave-uniform base; lane -> +lane*8 elems
  u16* dB = sB + wave * 512;
  auto stg = [&](int bo_, int k0) {
    gl2lds16(A0 + k0, dA + bo_);
    gl2lds16(B0 + k0, dB + bo_);
  };
  // Hoisted frag elem-offsets (kh=0 plane; kh=1 -> ^32 on elem index).
  int xa = (quad ^ (l15 & 7)) * 8;
  int aidx = (wm + l15) * 64 + xa;
  int bidx[2];
#pragma unroll
  for (int i = 0; i < 2; i++) bidx[i] = (wn + i * 16 + l15) * 64 + xa;

  f32x4 acc[2] = {};
  stg(0, 0);
  for (int t = 0; t < NT; t++) {
    int bo_ = (t & 1) * 4096;
    __builtin_amdgcn_s_barrier(); // B1: all waves done reading buf[t-1]
    if (t + 1 < NT) {
      stg(bo_ ^ 4096, (t + 1) * 64);
      asm volatile("s_waitcnt vmcnt(2)" ::: "memory"); // stage(t) landed
    } else {
      asm volatile("s_waitcnt vmcnt(0)" ::: "memory");
    }
    __builtin_amdgcn_s_barrier(); // B2: all waves' stage(t) landed
#pragma unroll
    for (int kh = 0; kh < 2; kh++) {
      int xk = kh * 32;
      bf8v af = *(const bf8v*)(sA + bo_ + (aidx ^ xk));
      bf8v bf[2];
#pragma unroll
      for (int i = 0; i < 2; i++)
        bf[i] = *(const bf8v*)(sB + bo_ + (bidx[i] ^ xk));
#pragma unroll
      for (int ni = 0; ni < 2; ni++)
        acc[ni] = __builtin_amdgcn_mfma_f32_16x16x32_bf16(af, bf[ni],
                                                          acc[ni], 0, 0, 0);
    }
  }
  float bvv[2];
#pragma unroll
  for (int ni = 0; ni < 2; ni++) bvv[ni] = bo[n0 + wn + ni * 16 + l15];
#pragma unroll
  for (int r = 0; r < 4; r++) {
    size_t ro = (size_t)(m0 + wm + quad * 4 + r) * D_MODEL + n0 + wn;
#pragma unroll
    for (int ni = 0; ni < 2; ni++)
      Cout[ro + ni * 16 + l15] = acc[ni][r] + bvv[ni];
  }
}

// ---------------------------------------------------------------------------
// Flash attention v10h (R8-exact, PASSING): grid (T/128, B*H) XCD-swizzled,
// 512 thr = 8 waves. Wave w: q sub-tile qw = w&3 (32 rows), key half
// kh = w>>2. exp2-native softmax without max-subtraction => key halves
// accumulate independent unnormalized (O, l), merged once at the end via
// LDS. K/V double-buffered global_load_lds DMA, ONE __syncthreads per tile.
// P transpose IN-REGISTER (cvt_pk + permlane swaps) with EXPLICIT s_nop
// wait-states (LLVM does not insert hazard nops across inline-asm
// boundaries; VALU-write -> cross-lane-read needs wait states).
__global__ __launch_bounds__(512, 4) void k_attn(
    const u16* __restrict__ Qr, const u16* __restrict__ Kr,
    const u16* __restrict__ Vb, const float* __restrict__ frac,
    const float* __restrict__ alpha_pos, const float* __restrict__ alpha_neg,
    u16* __restrict__ ctx) {
  // smem carve (u16 elems):
  //   [0,8192)       kT[2][4096]  swizzled [key][d]
  //   [8192,16384)   vT[2][4096]  swizzled [d][key]
  //   [16384,20480)  fLds: f32[2048] frac row for this batch
  // merge phase reuses [0,16896) as f32 O-scratch, [16896,17152) l-scratch.
  __shared__ __align__(16) u16 smem[20480];
  // ---- XCD swizzle: lin%8 = XCD (round-robin). Give each XCD 4 whole heads
  // so all 16 q-blocks of a head share one L2 (K/V single-fetch per XCD).
  int lin = blockIdx.x + (blockIdx.y << 4);
  int xcd = lin & 7, slot = lin >> 3;
  int bh = (xcd << 2) | (slot >> 4);
  int q0 = (slot & 15) << 7;
  int b = bh >> 4, h = bh & 15;
  int tid = threadIdx.x, wave = tid >> 6, lane = tid & 63;
  int l15 = lane & 15, quad = lane >> 4;
  int qw = wave & 3;  // q sub-tile (32 rows)
  int kh = wave >> 2; // key half within each 64-key tile

  const u16* Kh = Kr + (size_t)b * T_SEQ * D_MODEL + h * HDIM;
  const u16* Vh = Vb + (size_t)bh * HDIM * T_SEQ;
  const float* fb = frac + b * T_SEQ;

  u16* kT0 = smem;
  u16* vT0 = smem + 8192;
  float* fl = (float*)(smem + 16384);

  // Q B-frags (B[k=d][n=q] = Q[q][d]): lane holds Q[q=l15][d=quad*8+j]
  bf8v qf[2][2];
  float fq[2];
#pragma unroll
  for (int g = 0; g < 2; g++) {
    int qrow = q0 + qw * 32 + g * 16 + l15;
    const u16* qbase =
        Qr + (size_t)(b * T_SEQ + qrow) * D_MODEL + h * HDIM + quad * 8;
    qf[g][0] = *(const bf8v*)qbase;
    qf[g][1] = *(const bf8v*)(qbase + 32);
    fq[g] = fb[qrow]; // S^T col = q = l15
  }
  // frac -> LDS (512 thr x 4 floats = 2048)
  {
    f32x4 fv = *(const f32x4*)(fb + (tid << 2));
    *(f32x4*)(fl + (tid << 2)) = fv;
  }

  // bias = ap*max(dd,0)+an*min(dd,0) = c1*dd + c2*|dd| (log2 domain)
  float ap = alpha_pos[h] * LOG2E, an = alpha_neg[h] * LOG2E;
  float c1 = 0.5f * (ap + an), c2 = 0.5f * (ap - an);
  bf8v onesv;
#pragma unroll
  for (int j = 0; j < 8; j++) onesv[j] = (__bf16)1.0f;
  f32x4 zero4 = {};
  f32x4 o[2][4] = {};
  f32x4 o_l[2] = {};

  // Hoisted frag offsets (elems). Swizzle: row r, chunk gc -> pc = gc^(r&7).
  int x0 = (quad ^ (l15 & 7)) * 8;
  int kidx[2], vidx[4];
#pragma unroll
  for (int nt = 0; nt < 2; nt++) // K rows kh*32 + nt*16 + l15
    kidx[nt] = (((kh * 2 + nt) * 16 + l15) << 6) + x0;
#pragma unroll
  for (int dt = 0; dt < 4; dt++) // V keys chunk quad + kh*4
    vidx[dt] = (((dt * 16 + l15) << 6) + x0) ^ (kh * 32);

  // DMA staging map: 512 threads x 1 chunk per array per tile.
  // chunk p = tid; row = p>>3, pc = p&7; fetch global chunk gc = pc^(row&7).
  int kr0 = tid >> 3, gc0 = (tid & 7) ^ (kr0 & 7);
  const u16* kg0 = Kh + (size_t)kr0 * D_MODEL + gc0 * 8;
  const u16* vg0 = Vh + (size_t)kr0 * T_SEQ + gc0 * 8; // row = d here
  int woff = wave * 512; // wave-uniform LDS dest (elems); lane -> +lane*8

  auto stage = [&](int bufoff, int kbase) {
    gl2lds16(kg0 + (size_t)kbase * D_MODEL, kT0 + bufoff + woff);
    gl2lds16(vg0 + kbase, vT0 + bufoff + woff);
  };

  stage(0, 0);
  __syncthreads(); // DMA + frac-LDS visible

#pragma unroll 2
  for (int kt = 0; kt < T_SEQ / 64; kt++) {
    int kbase = kt * 64;
    int bo = (kt & 1) * 4096;
    if (kt + 1 < T_SEQ / 64) stage(bo ^ 4096, kbase + 64);
    const u16* kb = kT0 + bo;
    const u16* vb = vT0 + bo;

    // K A-frags for this wave's key half: rows kh*32 + nt*16 + l15
    bf8v kf0[2], kf1[2];
#pragma unroll
    for (int nt = 0; nt < 2; nt++) {
      kf0[nt] = *(const bf8v*)(kb + kidx[nt]);
      kf1[nt] = *(const bf8v*)(kb + (kidx[nt] ^ 32));
    }
    // V B-frags: rows d = dt*16+l15; key chunks kh*4 + quad
    bf8v vf[4];
#pragma unroll
    for (int dt = 0; dt < 4; dt++) vf[dt] = *(const bf8v*)(vb + vidx[dt]);
    // frac[key] for this lane's 4 keys per nt (LDS, 16-lane broadcast)
    f32x4 fk4[2];
#pragma unroll
    for (int nt = 0; nt < 2; nt++)
      fk4[nt] = *(const f32x4*)(fl + kbase + kh * 32 + nt * 16 + quad * 4);

#pragma unroll
    for (int g = 0; g < 2; g++) {
      float fqg = fq[g];
      // wrd = [A0, A1, B0, B1]: A_m from nt0 keys {4q+2m,+1}, B_m from nt1.
      unsigned int wrd[4];
#pragma unroll
      for (int nt = 0; nt < 2; nt++) {
        // S^T tile: D[row=key_loc=nt*16+quad*4+r][col=q=l15], log2 domain
        f32x4 s = zero4;
        s = __builtin_amdgcn_mfma_f32_16x16x32_bf16(kf0[nt], qf[g][0], s, 0, 0, 0);
        s = __builtin_amdgcn_mfma_f32_16x16x32_bf16(kf1[nt], qf[g][1], s, 0, 0, 0);
        float p[4];
#pragma unroll
        for (int r = 0; r < 4; r++) {
          float dd = fk4[nt][r] - fqg;
          p[r] = __builtin_amdgcn_exp2f(
              fmaf(c2, __builtin_fabsf(dd), fmaf(c1, dd, s[r])));
        }
        unsigned int w0, w1;
        asm("v_cvt_pk_bf16_f32 %0, %1, %2" : "=v"(w0) : "v"(p[0]), "v"(p[1]));
        asm("v_cvt_pk_bf16_f32 %0, %1, %2" : "=v"(w1) : "v"(p[2]), "v"(p[3]));
        wrd[nt * 2 + 0] = w0;
        wrd[nt * 2 + 1] = w1;
      }
      // In-register P transpose. permlane32_swap: X'={Xq0,Xq1,Yq0,Yq1},
      // Y'={Xq2,Xq3,Yq2,Yq3}. permlane16_swap: X''={X'r0,Y'r0,X'r2,Y'r2},
      // Y''={X'r1,Y'r1,X'r3,Y'r3}. (A0,B0)->(W0,W2); (A1,B1)->(W1,W3):
      // lane quad q ends with keys {8q..8q+7} = PV A-frag for m=l15.
      // s_nop guards: VALU-write -> cross-lane-read wait states are NOT
      // auto-inserted across inline-asm boundaries by LLVM (R7/R8-proven).
      asm volatile("s_nop 1" ::: "memory"); // cvt_pk writes -> permlane reads
      asm("v_permlane32_swap_b32 %0, %1" : "+v"(wrd[0]), "+v"(wrd[2]));
      asm("v_permlane32_swap_b32 %0, %1" : "+v"(wrd[1]), "+v"(wrd[3]));
      asm volatile("s_nop 1" ::: "memory"); // permlane32 -> dependent permlane16
      asm("v_permlane16_swap_b32 %0, %1" : "+v"(wrd[0]), "+v"(wrd[2]));
      asm("v_permlane16_swap_b32 %0, %1" : "+v"(wrd[1]), "+v"(wrd[3]));
      asm volatile("s_nop 1" ::: "memory"); // permlane16 -> MFMA src read
      u32x4v pw_;
      pw_.x = wrd[0]; pw_.y = wrd[1]; pw_.z = wrd[2]; pw_.w = wrd[3];
      bf8v pf = __builtin_bit_cast(bf8v, pw_);
      // O_g += P_g @ V_half ; l_g += P_g @ ones.
      o_l[g] = __builtin_amdgcn_mfma_f32_16x16x32_bf16(pf, onesv, o_l[g], 0, 0, 0);
#pragma unroll
      for (int dt = 0; dt < 4; dt++)
        o[g][dt] = __builtin_amdgcn_mfma_f32_16x16x32_bf16(pf, vf[dt],
                                                           o[g][dt], 0, 0, 0);
    }
    __syncthreads(); // drains this iter's DMA (vmcnt) + frees cur buf
  }

  // ---- merge key halves. kh==1 waves publish (O,l); kh==0 combine+store.
  float* Of = (float*)smem;             // [128 q][66] f32 = 33792 B
  float* Lf = (float*)(smem + 16896);   // 128 f32
  if (kh == 1) {
#pragma unroll
    for (int g = 0; g < 2; g++)
#pragma unroll
      for (int r = 0; r < 4; r++) {
        int ql = qw * 32 + g * 16 + quad * 4 + r;
#pragma unroll
        for (int dt = 0; dt < 4; dt++)
          Of[ql * 66 + dt * 16 + l15] = o[g][dt][r];
        if (l15 == 0) Lf[ql] = o_l[g][r];
      }
  }
  __syncthreads();
  if (kh == 0) {
#pragma unroll
    for (int g = 0; g < 2; g++)
#pragma unroll
      for (int r = 0; r < 4; r++) {
        int ql = qw * 32 + g * 16 + quad * 4 + r;
        float linv = 1.0f / (o_l[g][r] + Lf[ql]);
        __bf16* orow =
            (__bf16*)(ctx + (size_t)(b * T_SEQ + q0 + ql) * D_MODEL + h * HDIM);
#pragma unroll
        for (int dt = 0; dt < 4; dt++)
          orow[dt * 16 + l15] =
              (__bf16)((o[g][dt][r] + Of[ql * 66 + dt * 16 + l15]) * linv);
      }
  }
}

// ---------------------------------------------------------------------------
extern "C" void kernel_launch(void* const* d_in, const int* in_sizes, int n_in,
                              void* d_out, int out_size, void* d_ws,
                              size_t ws_size, hipStream_t stream) {
  const float* q = (const float*)d_in[0];
  const float* k = (const float*)d_in[1];
  const float* v = (const float*)d_in[2];
  const float* frac = (const float*)d_in[3];
  const float* Wq = (const float*)d_in[4];
  const float* Wk = (const float*)d_in[5];
  const float* Wv = (const float*)d_in[6];
  const float* Wo = (const float*)d_in[7];
  const float* bq = (const float*)d_in[8];
  const float* bk = (const float*)d_in[9];
  const float* bv = (const float*)d_in[10];
  const float* bo = (const float*)d_in[11];
  const float* alpha_pos = (const float*)d_in[12];
  const float* alpha_neg = (const float*)d_in[13];

  char* ws = (char*)d_ws;
  u16* Xb = (u16*)(ws + 0);
  u16* Wt = (u16*)(ws + 25165824);
  u16* Qr = (u16*)(ws + 33554432);
  u16* Kr = (u16*)(ws + 41943040);
  u16* Vtmp = (u16*)(ws + 50331648); // holds ctx
  u16* Vb = (u16*)(ws + 58720256);
  float* ctab = (float*)(ws + 67108864);
  float* stab = (float*)(ws + 67371008);
  u16* ctx = Vtmp;
  u16* QKVout = Qr; // Qr,Kr contiguous; z==2 writes Vb directly

  k_prep<<<dim3(7424), 256, 0, stream>>>(q, k, v, Wq, Wk, Wv, Wo, Xb, Wt, ctab,
                                         stab);
  k_gemm_qkv<<<dim3(8, 32, 3), 512, 0, stream>>>(Xb, Wt, bq, bk, bv, ctab, stab,
                                                 QKVout, Vb);
  k_attn<<<dim3(16, 32), 512, 0, stream>>>(Qr, Kr, Vb, frac, alpha_pos,
                                           alpha_neg, ctx);
  k_gemm_out<<<dim3(16, 64), 512, 0, stream>>>(ctx, Wt + 3 * 1048576, bo,
                                               (float*)d_out);
}